// Round 9
// baseline (176.064 us; speedup 1.0000x reference)
//
#include <hip/hip_runtime.h>

#define T_DIM 8192
#define D_DIM 256
#define N_DIM 64
#define LOG2E 1.44269504f

typedef __bf16 bf16x8 __attribute__((ext_vector_type(8)));
typedef __bf16 bf16x4 __attribute__((ext_vector_type(4)));
typedef float f32x16 __attribute__((ext_vector_type(16)));

__device__ __forceinline__ f32x16 zero16() {
  f32x16 v;
#pragma unroll
  for (int i = 0; i < 16; ++i) v[i] = 0.f;
  return v;
}

// Fragment-major layout (DHf and Hf): for a 32-row group G, chunk c=kk*2+h,
// lane l31: buf[G*2048 + c*256 + l31*8 .. +7]. A wave loading chunk kk reads
// buf + G*2048 + kk*512 + lane*8 -> one coalesced 1 KB instruction.

// ---------------------------------------------------------------------------
// K1: DHf (bf16, fragment-major) via split-bf16 MFMA, lbe[t]=lb*log2e,
//     rowsum[t]=0. grid 128 x 256.
// ---------------------------------------------------------------------------
__global__ __launch_bounds__(256) void k_dh(const float* __restrict__ H,
                                            const float* __restrict__ Dm,
                                            __bf16* __restrict__ DHf,
                                            float* __restrict__ lbe,
                                            float* __restrict__ rowsum) {
  __shared__ __bf16 HlThi[64 * 264];
  __shared__ __bf16 HlTlo[64 * 264];
  __shared__ __bf16 DHs[64 * 72];
  const int tid = threadIdx.x;
  const int t0 = blockIdx.x * 64;
  const int lane = tid & 63;
  const int wave = tid >> 6;
  const int h = lane >> 5;
  const int l31 = lane & 31;
  const float4* H4 = (const float4*)H;
#pragma unroll
  for (int r = 0; r < 16; ++r) {
    int idx = r * 256 + tid;
    int d = idx >> 4, tc = idx & 15;
    float4 v = H4[(size_t)d * (T_DIM / 4) + (t0 >> 2) + tc];
    float vv[4] = {v.x, v.y, v.z, v.w};
#pragma unroll
    for (int i = 0; i < 4; ++i) {
      __bf16 hi = (__bf16)vv[i];
      float lo = vv[i] - (float)hi;
      HlThi[(tc * 4 + i) * 264 + d] = hi;
      HlTlo[(tc * 4 + i) * 264 + d] = (__bf16)lo;
    }
  }
  __syncthreads();
  const int tt = wave & 1, nh = wave >> 1;
  const int m = tt * 32 + l31;
  const int n = nh * 32 + l31;
  f32x16 c = zero16();
  for (int kk = 0; kk < 16; ++kk) {
    bf16x8 ahi = *(const bf16x8*)&HlThi[m * 264 + kk * 16 + h * 8];
    bf16x8 alo = *(const bf16x8*)&HlTlo[m * 264 + kk * 16 + h * 8];
    const float4* dp = (const float4*)(Dm + (size_t)n * 256 + kk * 16 + h * 8);
    float4 b0 = dp[0], b1 = dp[1];
    float bv[8] = {b0.x, b0.y, b0.z, b0.w, b1.x, b1.y, b1.z, b1.w};
    bf16x8 bhi, blo;
#pragma unroll
    for (int i = 0; i < 8; ++i) {
      __bf16 hi = (__bf16)bv[i];
      bhi[i] = hi;
      blo[i] = (__bf16)(bv[i] - (float)hi);
    }
    c = __builtin_amdgcn_mfma_f32_32x32x16_bf16(ahi, bhi, c, 0, 0, 0);
    c = __builtin_amdgcn_mfma_f32_32x32x16_bf16(ahi, blo, c, 0, 0, 0);
    c = __builtin_amdgcn_mfma_f32_32x32x16_bf16(alo, bhi, c, 0, 0, 0);
  }
#pragma unroll
  for (int r = 0; r < 16; ++r) {
    int row = tt * 32 + (r & 3) + 8 * (r >> 2) + 4 * h;
    DHs[row * 72 + n] = (__bf16)c[r];
  }
  __syncthreads();
#pragma unroll
  for (int r = 0; r < 2; ++r) {
    int idx = r * 256 + tid;
    int g = idx >> 8, cc = (idx >> 5) & 7, l = idx & 31;
    bf16x8 w = *(const bf16x8*)&DHs[(g * 32 + l) * 72 + cc * 8];
    *(bf16x8*)(DHf + (size_t)(blockIdx.x * 2 + g) * 2048 + cc * 256 + l * 8) = w;
  }
  if (tid < 64) {
    float s = 0.f;
#pragma unroll
    for (int q = 0; q < 8; ++q) {
      bf16x8 w = *(const bf16x8*)&DHs[tid * 72 + q * 8];
#pragma unroll
      for (int i = 0; i < 8; ++i) { float f = (float)w[i]; s += f * f; }
    }
    lbe[t0 + tid] = -0.5f * s * LOG2E;
    rowsum[t0 + tid] = 0.f;
  }
}

// ---------------------------------------------------------------------------
// K2: rowsum[t] += sum_j exp(S+lb). grid 2048 x 256 (t 64 x j-range 512).
// ---------------------------------------------------------------------------
__global__ __launch_bounds__(256, 2) void k_rowsum(const __bf16* __restrict__ DHf,
                                                   const float* __restrict__ lbe,
                                                   float* __restrict__ rowsum) {
  __shared__ float red2[64 * 65];
  const int tid = threadIdx.x;
  const int lane = tid & 63;
  const int wave = tid >> 6;
  const int h = lane >> 5;
  const int tt = wave & 1, jt = wave >> 1;
  const int t0 = (int)(blockIdx.x >> 4) * 64;
  const int jbase = (int)(blockIdx.x & 15) * 512;
  const int Gt = (t0 >> 5) + tt;
  bf16x8 aR[4];
#pragma unroll
  for (int kk = 0; kk < 4; ++kk)
    aR[kk] = *(const bf16x8*)(DHf + (size_t)Gt * 2048 + kk * 512 + lane * 8);
  float racc[16];
#pragma unroll
  for (int r = 0; r < 16; ++r) racc[r] = 0.f;
  for (int jit = 0; jit < 8; ++jit) {
    const size_t Gj = (jbase >> 5) + jit * 2 + jt;
    bf16x8 b[4];
#pragma unroll
    for (int kk = 0; kk < 4; ++kk)
      b[kk] = *(const bf16x8*)(DHf + Gj * 2048 + kk * 512 + lane * 8);
    const float lbv = lbe[jbase + jit * 64 + jt * 32 + (lane & 31)];
    f32x16 s = zero16();
#pragma unroll
    for (int kk = 0; kk < 4; ++kk)
      s = __builtin_amdgcn_mfma_f32_32x32x16_bf16(aR[kk], b[kk], s, 0, 0, 0);
#pragma unroll
    for (int r = 0; r < 16; ++r)
      racc[r] += __builtin_amdgcn_exp2f(__builtin_fmaf(s[r], LOG2E, lbv));
  }
#pragma unroll
  for (int r = 0; r < 16; ++r) {
    int tl = tt * 32 + (r & 3) + 8 * (r >> 2) + 4 * h;
    red2[tl * 65 + jt * 32 + (lane & 31)] = racc[r];
  }
  __syncthreads();
  if (tid < 64) {
    float s = 0.f;
#pragma unroll 8
    for (int c = 0; c < 64; ++c) s += red2[tid * 65 + c];
    atomicAdd(&rowsum[t0 + tid], s);
  }
}

// ---------------------------------------------------------------------------
// K2b: Hf = bf16(H*rinv[t]) in FRAGMENT-MAJOR layout (per 64-t block:
//      group (tblk*8 + d>>5), chunk c = local_t>>3, lane d&31). Zeroes Z.
//      grid 256 x 256.
// ---------------------------------------------------------------------------
__global__ __launch_bounds__(256) void k_scaleH(const float* __restrict__ H,
                                                const float* __restrict__ rowsum,
                                                __bf16* __restrict__ Hf,
                                                float* __restrict__ Z) {
  __shared__ float rinvL[64];
  const int tid = threadIdx.x;
  const int bx = blockIdx.x;
  const int tblk = bx >> 1, dh = bx & 1;
  const int t0 = tblk * 64;
  if (tid < 64) rinvL[tid] = 1.0f / rowsum[t0 + tid];
  __syncthreads();
#pragma unroll
  for (int itr = 0; itr < 4; ++itr) {
    int idx = itr * 256 + tid;  // 1024 chunks of 8 t
    int dl = idx >> 3, c = idx & 7;
    int d = dh * 128 + dl;
    int tloc = c * 8;
    const float4* hp = (const float4*)(H + (size_t)d * T_DIM + t0 + tloc);
    float4 v0 = hp[0], v1 = hp[1];
    float4 r0 = *(const float4*)&rinvL[tloc];
    float4 r1 = *(const float4*)&rinvL[tloc + 4];
    bf16x8 w;
    w[0] = (__bf16)(v0.x * r0.x); w[1] = (__bf16)(v0.y * r0.y);
    w[2] = (__bf16)(v0.z * r0.z); w[3] = (__bf16)(v0.w * r0.w);
    w[4] = (__bf16)(v1.x * r1.x); w[5] = (__bf16)(v1.y * r1.y);
    w[6] = (__bf16)(v1.z * r1.z); w[7] = (__bf16)(v1.w * r1.w);
    *(bf16x8*)(Hf + (size_t)(tblk * 8 + (d >> 5)) * 2048 + c * 256 + (d & 31) * 8) = w;
  }
  float4* Z4 = (float4*)Z;
  const int base = bx * 256 + tid;
  const float4 z4 = {0.f, 0.f, 0.f, 0.f};
#pragma unroll
  for (int r = 0; r < 8; ++r) Z4[r * 65536 + base] = z4;
}

// ---------------------------------------------------------------------------
// K3: Z[d][j] += l2 * sum_t H'[d][t] * E[t][j].
//     grid 512 = 64 j-tiles(128) x 2 d-halves(128) x 4 t-splits(2048).
//     SINGLE barrier per iter: Pt double-buffered; A-fragments of the Z-GEMM
//     loaded directly from fragment-major Hf (global, L2-resident) -- no LDS
//     staging, no DMA drain. LDS 32 KB -> 3 blocks/CU.
// ---------------------------------------------------------------------------
__global__ __launch_bounds__(256, 3) void k_z(const __bf16* __restrict__ Hf,
                                              const __bf16* __restrict__ DHf,
                                              const float* __restrict__ lbe,
                                              const float* __restrict__ l2p,
                                              float* __restrict__ Z) {
  __shared__ __bf16 Pt[2][128 * 64];  // [j][t] swizzled, 2 x 16 KB
  const int tid = threadIdx.x;
  const int lane = tid & 63;
  const int wave = tid >> 6;
  const int h = lane >> 5;
  const int l31 = lane & 31;
  const int bx = blockIdx.x;
  const int ts = bx & 3;
  const int dh = (bx >> 2) & 1;
  const int j0 = (bx >> 3) * 128;
  const int tbase = ts * 2048;
  const float l2v = l2p[0];
  const int s_tt = wave & 1, s_jg = wave >> 1;
  // resident S-phase B fragments + lbe
  bf16x8 bS[2][4];
  float lbv[2];
#pragma unroll
  for (int q = 0; q < 2; ++q) {
    const size_t Gj = (j0 >> 5) + s_jg * 2 + q;
#pragma unroll
    for (int kk = 0; kk < 4; ++kk)
      bS[q][kk] = *(const bf16x8*)(DHf + Gj * 2048 + kk * 512 + lane * 8);
    lbv[q] = lbe[j0 + (s_jg * 2 + q) * 32 + l31];
  }
  f32x16 acc[2][2];
#pragma unroll
  for (int u = 0; u < 2; ++u)
#pragma unroll
    for (int v = 0; v < 2; ++v) acc[u][v] = zero16();

  bf16x8 aR[4];
#pragma unroll
  for (int kk = 0; kk < 4; ++kk)  // A frags for it=0
    aR[kk] = *(const bf16x8*)(DHf + (size_t)(ts * 64 + s_tt) * 2048 + kk * 512 + lane * 8);

  // S-phase into Pt[p] for tile index 'it' using current aR
#define S_PHASE(p_, it_)                                                        \
  {                                                                             \
    _Pragma("unroll") for (int q = 0; q < 2; ++q) {                             \
      f32x16 s = zero16();                                                      \
      _Pragma("unroll") for (int kk = 0; kk < 4; ++kk)                          \
          s = __builtin_amdgcn_mfma_f32_32x32x16_bf16(aR[kk], bS[q][kk], s, 0,  \
                                                      0, 0);                    \
      const int jl = (s_jg * 2 + q) * 32 + l31;                                 \
      const int sj = (jl ^ (jl >> 3)) & 7;                                      \
      _Pragma("unroll") for (int g = 0; g < 4; ++g) {                           \
        const int tl = s_tt * 32 + g * 8 + 4 * h;                               \
        bf16x4 pv;                                                              \
        pv[0] = (__bf16)__builtin_amdgcn_exp2f(                                 \
            __builtin_fmaf(s[g * 4 + 0], LOG2E, lbv[q]));                       \
        pv[1] = (__bf16)__builtin_amdgcn_exp2f(                                 \
            __builtin_fmaf(s[g * 4 + 1], LOG2E, lbv[q]));                       \
        pv[2] = (__bf16)__builtin_amdgcn_exp2f(                                 \
            __builtin_fmaf(s[g * 4 + 2], LOG2E, lbv[q]));                       \
        pv[3] = (__bf16)__builtin_amdgcn_exp2f(                                 \
            __builtin_fmaf(s[g * 4 + 3], LOG2E, lbv[q]));                       \
        const int cchunk = tl >> 3;                                             \
        *(bf16x4*)&Pt[p_][jl * 64 + ((cchunk ^ sj) << 3) + 4 * h] = pv;         \
      }                                                                         \
    }                                                                           \
  }

  S_PHASE(0, 0);
  // prefetch A frags for it=1
#pragma unroll
  for (int kk = 0; kk < 4; ++kk)
    aR[kk] = *(const bf16x8*)(DHf + (size_t)(ts * 64 + 2 + s_tt) * 2048 + kk * 512 + lane * 8);

  for (int it = 0; it < 32; ++it) {
    const int p = it & 1;
    __syncthreads();  // Pt[p] complete; previous Z done reading Pt[p^1]
    if (it < 31) S_PHASE(p ^ 1, it + 1);
    if (it < 30) {
      const size_t Gt = ts * 64 + (it + 2) * 2 + s_tt;
#pragma unroll
      for (int kk = 0; kk < 4; ++kk)
        aR[kk] = *(const bf16x8*)(DHf + Gt * 2048 + kk * 512 + lane * 8);
    }
    // ---- Z phase: af direct from global Hf (fragment-major, coalesced) ----
    const size_t hbase = (size_t)((ts * 32 + it) * 8) * 2048;
#pragma unroll
    for (int kk = 0; kk < 4; ++kk) {
      bf16x8 af[2], bw[2];
#pragma unroll
      for (int u = 0; u < 2; ++u) {
        const int dgrp = dh * 4 + (wave & 1) * 2 + u;
        af[u] = *(const bf16x8*)(Hf + hbase + (size_t)dgrp * 2048 + kk * 512 + lane * 8);
      }
      const int c = kk * 2 + h;
#pragma unroll
      for (int v = 0; v < 2; ++v) {
        int j = (wave >> 1) * 64 + v * 32 + l31;
        bw[v] = *(const bf16x8*)&Pt[p][j * 64 + ((c ^ ((j ^ (j >> 3)) & 7)) << 3)];
      }
#pragma unroll
      for (int u = 0; u < 2; ++u)
#pragma unroll
        for (int v = 0; v < 2; ++v)
          acc[u][v] = __builtin_amdgcn_mfma_f32_32x32x16_bf16(af[u], bw[v], acc[u][v], 0, 0, 0);
    }
  }
#undef S_PHASE
  // ---- epilogue ----
#pragma unroll
  for (int u = 0; u < 2; ++u)
#pragma unroll
    for (int v = 0; v < 2; ++v)
#pragma unroll
      for (int r = 0; r < 16; ++r) {
        int d = dh * 128 + (wave & 1) * 64 + u * 32 + (r & 3) + 8 * (r >> 2) + 4 * h;
        int j = j0 + (wave >> 1) * 64 + v * 32 + l31;
        atomicAdd(&Z[(size_t)d * T_DIM + j], acc[u][v][r] * l2v);
      }
}

// ---------------------------------------------------------------------------
extern "C" void kernel_launch(void* const* d_in, const int* in_sizes, int n_in,
                              void* d_out, int out_size, void* d_ws,
                              size_t ws_size, hipStream_t stream) {
  (void)in_sizes; (void)n_in; (void)out_size; (void)ws_size;
  const float* H = (const float*)d_in[0];
  const float* Dm = (const float*)d_in[1];
  const float* l2 = (const float*)d_in[2];
  float* Z = (float*)d_out;
  char* ws = (char*)d_ws;
  __bf16* DHf = (__bf16*)ws;                      // 1,048,576 B
  float* lbe = (float*)(ws + 1048576);            // 32,768 B
  float* rowsum = (float*)(ws + 1048576 + 32768); // 32,768 B
  __bf16* Hf = (__bf16*)(ws + 1048576 + 65536);   // 4,194,304 B

  k_dh<<<128, 256, 0, stream>>>(H, Dm, DHf, lbe, rowsum);
  k_rowsum<<<2048, 256, 0, stream>>>(DHf, lbe, rowsum);
  k_scaleH<<<256, 256, 0, stream>>>(H, rowsum, Hf, Z);
  k_z<<<512, 256, 0, stream>>>(Hf, DHf, lbe, l2, Z);
}

// Round 10
// 160.312 us; speedup vs baseline: 1.0983x; 1.0983x over previous
//
#include <hip/hip_runtime.h>

#define T_DIM 8192
#define D_DIM 256
#define N_DIM 64
#define LOG2E 1.44269504f

typedef __bf16 bf16x8 __attribute__((ext_vector_type(8)));
typedef __bf16 bf16x4 __attribute__((ext_vector_type(4)));
typedef float f32x16 __attribute__((ext_vector_type(16)));

__device__ __forceinline__ f32x16 zero16() {
  f32x16 v;
#pragma unroll
  for (int i = 0; i < 16; ++i) v[i] = 0.f;
  return v;
}

// DHf: fragment-major. Row-group G=row>>5, chunk c=kk*2+h, lane l31:
// DHf[G*2048 + c*256 + l31*8 .. +7]; wave load = base + lane*16B, coalesced.

// ---------------------------------------------------------------------------
// K1: DHf (bf16, fragment-major) via split-bf16 MFMA, lbe[t]=lb*log2e,
//     rowsum[t]=0. grid 128 x 256.
// ---------------------------------------------------------------------------
__global__ __launch_bounds__(256) void k_dh(const float* __restrict__ H,
                                            const float* __restrict__ Dm,
                                            __bf16* __restrict__ DHf,
                                            float* __restrict__ lbe,
                                            float* __restrict__ rowsum) {
  __shared__ __bf16 HlThi[64 * 264];
  __shared__ __bf16 HlTlo[64 * 264];
  __shared__ __bf16 DHs[64 * 72];
  const int tid = threadIdx.x;
  const int t0 = blockIdx.x * 64;
  const int lane = tid & 63;
  const int wave = tid >> 6;
  const int h = lane >> 5;
  const int l31 = lane & 31;
  const float4* H4 = (const float4*)H;
#pragma unroll
  for (int r = 0; r < 16; ++r) {
    int idx = r * 256 + tid;
    int d = idx >> 4, tc = idx & 15;
    float4 v = H4[(size_t)d * (T_DIM / 4) + (t0 >> 2) + tc];
    float vv[4] = {v.x, v.y, v.z, v.w};
#pragma unroll
    for (int i = 0; i < 4; ++i) {
      __bf16 hi = (__bf16)vv[i];
      float lo = vv[i] - (float)hi;
      HlThi[(tc * 4 + i) * 264 + d] = hi;
      HlTlo[(tc * 4 + i) * 264 + d] = (__bf16)lo;
    }
  }
  __syncthreads();
  const int tt = wave & 1, nh = wave >> 1;
  const int m = tt * 32 + l31;
  const int n = nh * 32 + l31;
  f32x16 c = zero16();
  for (int kk = 0; kk < 16; ++kk) {
    bf16x8 ahi = *(const bf16x8*)&HlThi[m * 264 + kk * 16 + h * 8];
    bf16x8 alo = *(const bf16x8*)&HlTlo[m * 264 + kk * 16 + h * 8];
    const float4* dp = (const float4*)(Dm + (size_t)n * 256 + kk * 16 + h * 8);
    float4 b0 = dp[0], b1 = dp[1];
    float bv[8] = {b0.x, b0.y, b0.z, b0.w, b1.x, b1.y, b1.z, b1.w};
    bf16x8 bhi, blo;
#pragma unroll
    for (int i = 0; i < 8; ++i) {
      __bf16 hi = (__bf16)bv[i];
      bhi[i] = hi;
      blo[i] = (__bf16)(bv[i] - (float)hi);
    }
    c = __builtin_amdgcn_mfma_f32_32x32x16_bf16(ahi, bhi, c, 0, 0, 0);
    c = __builtin_amdgcn_mfma_f32_32x32x16_bf16(ahi, blo, c, 0, 0, 0);
    c = __builtin_amdgcn_mfma_f32_32x32x16_bf16(alo, bhi, c, 0, 0, 0);
  }
#pragma unroll
  for (int r = 0; r < 16; ++r) {
    int row = tt * 32 + (r & 3) + 8 * (r >> 2) + 4 * h;
    DHs[row * 72 + n] = (__bf16)c[r];
  }
  __syncthreads();
#pragma unroll
  for (int r = 0; r < 2; ++r) {
    int idx = r * 256 + tid;
    int g = idx >> 8, cc = (idx >> 5) & 7, l = idx & 31;
    bf16x8 w = *(const bf16x8*)&DHs[(g * 32 + l) * 72 + cc * 8];
    *(bf16x8*)(DHf + (size_t)(blockIdx.x * 2 + g) * 2048 + cc * 256 + l * 8) = w;
  }
  if (tid < 64) {
    float s = 0.f;
#pragma unroll
    for (int q = 0; q < 8; ++q) {
      bf16x8 w = *(const bf16x8*)&DHs[tid * 72 + q * 8];
#pragma unroll
      for (int i = 0; i < 8; ++i) { float f = (float)w[i]; s += f * f; }
    }
    lbe[t0 + tid] = -0.5f * s * LOG2E;
    rowsum[t0 + tid] = 0.f;
  }
}

// ---------------------------------------------------------------------------
// K2: rowsum[t] += sum_j exp(S+lb). grid 2048 x 256.
// ---------------------------------------------------------------------------
__global__ __launch_bounds__(256, 2) void k_rowsum(const __bf16* __restrict__ DHf,
                                                   const float* __restrict__ lbe,
                                                   float* __restrict__ rowsum) {
  __shared__ float red2[64 * 65];
  const int tid = threadIdx.x;
  const int lane = tid & 63;
  const int wave = tid >> 6;
  const int h = lane >> 5;
  const int tt = wave & 1, jt = wave >> 1;
  const int t0 = (int)(blockIdx.x >> 4) * 64;
  const int jbase = (int)(blockIdx.x & 15) * 512;
  const int Gt = (t0 >> 5) + tt;
  bf16x8 aR[4];
#pragma unroll
  for (int kk = 0; kk < 4; ++kk)
    aR[kk] = *(const bf16x8*)(DHf + (size_t)Gt * 2048 + kk * 512 + lane * 8);
  float racc[16];
#pragma unroll
  for (int r = 0; r < 16; ++r) racc[r] = 0.f;
  for (int jit = 0; jit < 8; ++jit) {
    const size_t Gj = (jbase >> 5) + jit * 2 + jt;
    bf16x8 b[4];
#pragma unroll
    for (int kk = 0; kk < 4; ++kk)
      b[kk] = *(const bf16x8*)(DHf + Gj * 2048 + kk * 512 + lane * 8);
    const float lbv = lbe[jbase + jit * 64 + jt * 32 + (lane & 31)];
    f32x16 s = zero16();
#pragma unroll
    for (int kk = 0; kk < 4; ++kk)
      s = __builtin_amdgcn_mfma_f32_32x32x16_bf16(aR[kk], b[kk], s, 0, 0, 0);
#pragma unroll
    for (int r = 0; r < 16; ++r)
      racc[r] += __builtin_amdgcn_exp2f(__builtin_fmaf(s[r], LOG2E, lbv));
  }
#pragma unroll
  for (int r = 0; r < 16; ++r) {
    int tl = tt * 32 + (r & 3) + 8 * (r >> 2) + 4 * h;
    red2[tl * 65 + jt * 32 + (lane & 31)] = racc[r];
  }
  __syncthreads();
  if (tid < 64) {
    float s = 0.f;
#pragma unroll 8
    for (int c = 0; c < 64; ++c) s += red2[tid * 65 + c];
    atomicAdd(&rowsum[t0 + tid], s);
  }
}

// ---------------------------------------------------------------------------
// K2b: Hbf_sw = bf16(H*rinv[t]) pre-swizzled to k_z's LDS image; zeroes Z.
//      grid 256 x 256.  (R7-proven swizzled-image version.)
// ---------------------------------------------------------------------------
__global__ __launch_bounds__(256) void k_scaleH(const float* __restrict__ H,
                                                const float* __restrict__ rowsum,
                                                __bf16* __restrict__ Hbf_sw,
                                                float* __restrict__ Z) {
  __shared__ float rinvL[64];
  const int tid = threadIdx.x;
  const int bx = blockIdx.x;
  const int tblk = bx >> 1, dh = bx & 1;
  const int t0 = tblk * 64;
  if (tid < 64) rinvL[tid] = 1.0f / rowsum[t0 + tid];
  __syncthreads();
#pragma unroll
  for (int itr = 0; itr < 4; ++itr) {
    int idx = itr * 256 + tid;
    int dl = idx >> 3, tbp = idx & 7;
    int d = dh * 128 + dl;
    int swz = (d ^ (d >> 3)) & 7;
    int tloc = (tbp ^ swz) << 3;
    const float4* hp = (const float4*)(H + (size_t)d * T_DIM + t0 + tloc);
    float4 v0 = hp[0], v1 = hp[1];
    float4 r0 = *(const float4*)&rinvL[tloc];
    float4 r1 = *(const float4*)&rinvL[tloc + 4];
    bf16x8 w;
    w[0] = (__bf16)(v0.x * r0.x); w[1] = (__bf16)(v0.y * r0.y);
    w[2] = (__bf16)(v0.z * r0.z); w[3] = (__bf16)(v0.w * r0.w);
    w[4] = (__bf16)(v1.x * r1.x); w[5] = (__bf16)(v1.y * r1.y);
    w[6] = (__bf16)(v1.z * r1.z); w[7] = (__bf16)(v1.w * r1.w);
    *(bf16x8*)(Hbf_sw + (size_t)tblk * 16384 + (size_t)d * 64 + tbp * 8) = w;
  }
  float4* Z4 = (float4*)Z;
  const int base = bx * 256 + tid;
  const float4 z4 = {0.f, 0.f, 0.f, 0.f};
#pragma unroll
  for (int r = 0; r < 8; ++r) Z4[r * 65536 + base] = z4;
}

// ---------------------------------------------------------------------------
// K3: Z[d][j] += l2 * sum_t H'[d][t] * E[t][j].
//     grid 512 = 64 j-tiles(128) x 2 d-halves(128) x 4 t-splits(2048).
//     Hs AND Pt double-buffered (64 KB LDS): ONE barrier per iter; the
//     global_load_lds DMA for it+1 is issued at iter start and drained a
//     full iteration later -- prefetch stays in flight across the barrier.
//     2 blocks/CU.
// ---------------------------------------------------------------------------
__global__ __launch_bounds__(256, 2) void k_z(const __bf16* __restrict__ Hbf_sw,
                                              const __bf16* __restrict__ DHf,
                                              const float* __restrict__ lbe,
                                              const float* __restrict__ l2p,
                                              float* __restrict__ Z) {
  __shared__ __bf16 Hs[2][128 * 64];  // [dl][t] swizzled, 2 x 16 KB
  __shared__ __bf16 Pt[2][128 * 64];  // [j][t] swizzled,  2 x 16 KB
  const int tid = threadIdx.x;
  const int lane = tid & 63;
  const int wave = tid >> 6;
  const int h = lane >> 5;
  const int l31 = lane & 31;
  const int bx = blockIdx.x;
  const int ts = bx & 3;
  const int dh = (bx >> 2) & 1;
  const int j0 = (bx >> 3) * 128;
  const float l2v = l2p[0];
  const int s_tt = wave & 1, s_jg = wave >> 1;
  // resident S-phase B fragments + lbe
  bf16x8 bS[2][4];
  float lbv[2];
#pragma unroll
  for (int q = 0; q < 2; ++q) {
    const size_t Gj = (j0 >> 5) + s_jg * 2 + q;
#pragma unroll
    for (int kk = 0; kk < 4; ++kk)
      bS[q][kk] = *(const bf16x8*)(DHf + Gj * 2048 + kk * 512 + lane * 8);
    lbv[q] = lbe[j0 + (s_jg * 2 + q) * 32 + l31];
  }
  f32x16 acc[2][2];
#pragma unroll
  for (int u = 0; u < 2; ++u)
#pragma unroll
    for (int v = 0; v < 2; ++v) acc[u][v] = zero16();

  // DMA of H' tile 'it_' into Hs[buf_]
#define DMA_HS(buf_, it_)                                                       \
  {                                                                             \
    const __bf16* gsrc =                                                        \
        Hbf_sw + (size_t)(ts * 32 + (it_)) * 16384 + (size_t)dh * 8192;         \
    _Pragma("unroll") for (int r = 0; r < 4; ++r) {                             \
      int chunk = wave * 4 + r;                                                 \
      __builtin_amdgcn_global_load_lds(                                         \
          (const __attribute__((address_space(1))) unsigned int*)(gsrc +        \
              chunk * 512 + lane * 8),                                          \
          (__attribute__((address_space(3))) unsigned int*)(&Hs[buf_][0] +      \
              chunk * 512),                                                     \
          16, 0, 0);                                                            \
    }                                                                           \
  }

  // S-phase into Pt[p_] using current aR
#define S_PHASE(p_)                                                             \
  {                                                                             \
    _Pragma("unroll") for (int q = 0; q < 2; ++q) {                             \
      f32x16 s = zero16();                                                      \
      _Pragma("unroll") for (int kk = 0; kk < 4; ++kk)                          \
          s = __builtin_amdgcn_mfma_f32_32x32x16_bf16(aR[kk], bS[q][kk], s, 0,  \
                                                      0, 0);                    \
      const int jl = (s_jg * 2 + q) * 32 + l31;                                 \
      const int sj = (jl ^ (jl >> 3)) & 7;                                      \
      _Pragma("unroll") for (int g = 0; g < 4; ++g) {                           \
        const int tl = s_tt * 32 + g * 8 + 4 * h;                               \
        bf16x4 pv;                                                              \
        pv[0] = (__bf16)__builtin_amdgcn_exp2f(                                 \
            __builtin_fmaf(s[g * 4 + 0], LOG2E, lbv[q]));                       \
        pv[1] = (__bf16)__builtin_amdgcn_exp2f(                                 \
            __builtin_fmaf(s[g * 4 + 1], LOG2E, lbv[q]));                       \
        pv[2] = (__bf16)__builtin_amdgcn_exp2f(                                 \
            __builtin_fmaf(s[g * 4 + 2], LOG2E, lbv[q]));                       \
        pv[3] = (__bf16)__builtin_amdgcn_exp2f(                                 \
            __builtin_fmaf(s[g * 4 + 3], LOG2E, lbv[q]));                       \
        const int cchunk = tl >> 3;                                             \
        *(bf16x4*)&Pt[p_][jl * 64 + ((cchunk ^ sj) << 3) + 4 * h] = pv;         \
      }                                                                         \
    }                                                                           \
  }

  bf16x8 aR[4];
#pragma unroll
  for (int kk = 0; kk < 4; ++kk)  // A frags for it=0
    aR[kk] = *(const bf16x8*)(DHf + (size_t)(ts * 64 + s_tt) * 2048 + kk * 512 + lane * 8);
  // prologue: DMA Hs[0] (it=0), compute Pt[0] (it=0), prefetch aR(it=1)
  DMA_HS(0, 0);
  S_PHASE(0);
#pragma unroll
  for (int kk = 0; kk < 4; ++kk)
    aR[kk] = *(const bf16x8*)(DHf + (size_t)(ts * 64 + 2 + s_tt) * 2048 + kk * 512 + lane * 8);
  __syncthreads();  // Hs[0] drained, Pt[0] visible

  for (int it = 0; it < 32; ++it) {
    const int p = it & 1;
    // issue next tile's DMA + S-phase first (drain deferred to iter-end barrier)
    if (it < 31) {
      DMA_HS(p ^ 1, it + 1);
      S_PHASE(p ^ 1);  // consumes aR = frags(it+1)
    }
    if (it < 30) {
      const size_t Gt = ts * 64 + (it + 2) * 2 + s_tt;
#pragma unroll
      for (int kk = 0; kk < 4; ++kk)
        aR[kk] = *(const bf16x8*)(DHf + Gt * 2048 + kk * 512 + lane * 8);
    }
    // ---- Z phase from buffers p ----
#pragma unroll
    for (int kk = 0; kk < 4; ++kk) {
      const int c = kk * 2 + h;
      bf16x8 af[2], bw[2];
#pragma unroll
      for (int u = 0; u < 2; ++u) {
        int dl = (wave & 1) * 64 + u * 32 + l31;
        af[u] = *(const bf16x8*)&Hs[p][dl * 64 + ((c ^ ((dl ^ (dl >> 3)) & 7)) << 3)];
      }
#pragma unroll
      for (int v = 0; v < 2; ++v) {
        int j = (wave >> 1) * 64 + v * 32 + l31;
        bw[v] = *(const bf16x8*)&Pt[p][j * 64 + ((c ^ ((j ^ (j >> 3)) & 7)) << 3)];
      }
#pragma unroll
      for (int u = 0; u < 2; ++u)
#pragma unroll
        for (int v = 0; v < 2; ++v)
          acc[u][v] = __builtin_amdgcn_mfma_f32_32x32x16_bf16(af[u], bw[v], acc[u][v], 0, 0, 0);
    }
    __syncthreads();  // one barrier/iter: next buffers ready, DMA drained
  }
#undef S_PHASE
#undef DMA_HS
  // ---- epilogue ----
#pragma unroll
  for (int u = 0; u < 2; ++u)
#pragma unroll
    for (int v = 0; v < 2; ++v)
#pragma unroll
      for (int r = 0; r < 16; ++r) {
        int d = dh * 128 + (wave & 1) * 64 + u * 32 + (r & 3) + 8 * (r >> 2) + 4 * h;
        int j = j0 + (wave >> 1) * 64 + v * 32 + l31;
        atomicAdd(&Z[(size_t)d * T_DIM + j], acc[u][v][r] * l2v);
      }
}

// ---------------------------------------------------------------------------
extern "C" void kernel_launch(void* const* d_in, const int* in_sizes, int n_in,
                              void* d_out, int out_size, void* d_ws,
                              size_t ws_size, hipStream_t stream) {
  (void)in_sizes; (void)n_in; (void)out_size; (void)ws_size;
  const float* H = (const float*)d_in[0];
  const float* Dm = (const float*)d_in[1];
  const float* l2 = (const float*)d_in[2];
  float* Z = (float*)d_out;
  char* ws = (char*)d_ws;
  __bf16* DHf = (__bf16*)ws;                        // 1,048,576 B
  float* lbe = (float*)(ws + 1048576);              // 32,768 B
  float* rowsum = (float*)(ws + 1048576 + 32768);   // 32,768 B
  __bf16* Hbf_sw = (__bf16*)(ws + 1048576 + 65536); // 4,194,304 B

  k_dh<<<128, 256, 0, stream>>>(H, Dm, DHf, lbe, rowsum);
  k_rowsum<<<2048, 256, 0, stream>>>(DHf, lbe, rowsum);
  k_scaleH<<<256, 256, 0, stream>>>(H, rowsum, Hbf_sw, Z);
  k_z<<<512, 256, 0, stream>>>(Hbf_sw, DHf, lbe, l2, Z);
}